// Round 10
// baseline (9511.157 us; speedup 1.0000x reference)
//
#include <hip/hip_runtime.h>
#include <hip/hip_cooperative_groups.h>
#include <math.h>

namespace cg = cooperative_groups;

// ---------------- problem constants ----------------
#define K_BEAM  10
#define V_SZ    50257
#define E_SZ    128
#define H1_SZ   128
#define H2_SZ   64
#define Q_SZ    64
#define T_SZ    2048
#define MAXLEN  30
#define SEQ_LEN 31
#define SOS_TOK 1
#define EOS_TOK 2

#define NBLK 256
#define CB   256            // logits blocks (== NBLK)
#define VC   197            // ceil(V_SZ/CB); last block vn = 22

// ---------------- workspace layout (float indices; f64 at even idx) ----------
#define ST_A_F   0          // double[4480]
#define ST_B_F   8960
#define SD_H1    0
#define SD_C1    1280
#define SD_H2    2560
#define SD_C2    3200
#define SD_CTX   3840
#define META_A_F 17920
#define META_B_F 18272
#define M_SC     0
#define M_FIN    20
#define M_PREV   30
#define M_SEQ    40
#define H2V_F    18624      // double[640]
#define PICKV_F  19904      // double[10]
#define PICKF_F  19924      // int[10] (+pad)
#define GT1_F    19936      // double[5120]
#define QD_F     30176      // double[640]
#define MC_F     31456      // double[80]
#define SCC_F    31616      // double[80]
#define MSC_F    31776      // double[80]
#define CTXC_F   31936      // double[5120]
#define LSEM_F   42176      // double[2560]
#define LSES_F   47296      // double[2560]
#define CANDV_F  52416      // float[25600]
#define CANDI_F  78016      // int[25600]
#define SLM_F    103616     // double[80]  slice lse max
#define SLS_F    103776     // double[80]  slice lse sum
#define SV_F     103936     // float[800]  per-(beam,slice) top10 values
#define SF_F     104736     // int[800]    per-(beam,slice) top10 v-indices
// end ~105536 floats = 422 KiB (< 2.1 MB verified ws)

// ---------------- wave helpers ----------------
__device__ __forceinline__ void wave_argmax_f(float& v, int& i) {
  #pragma unroll
  for (int off = 32; off > 0; off >>= 1) {
    float ov = __shfl_down(v, off, 64);
    int   oi = __shfl_down(i, off, 64);
    if (ov > v || (ov == v && oi < i)) { v = ov; i = oi; }
  }
}
__device__ __forceinline__ void wave_argmax_d(double& v, int& i) {
  #pragma unroll
  for (int off = 32; off > 0; off >>= 1) {
    double ov = __shfl_down(v, off, 64);
    int    oi = __shfl_down(i, off, 64);
    if (ov > v || (ov == v && oi < i)) { v = ov; i = oi; }
  }
}

// ---------------- shared-memory union ----------------
struct SA  { double xin[192]; double h1p[128]; double lo[128]; double hi[128]; };
struct SB  { double h1n[128]; double h2p[64]; double gt2[256]; double h2n[64]; };
struct SCD { double qs[64]; double es[256]; double rm[256]; double rs[256]; double mx; double Ss; };
struct SE  { double xs[1280]; float lg[VC*K_BEAM]; };
struct SF_ { float cv[320]; int ci[320]; double lm[32]; double ls[32];
             float rv[256]; int ri[256]; float pv[10]; int pi[10]; };
struct SG  { double gv[100]; int gf[100]; };
struct SFN { int seqF[K_BEAM*SEQ_LEN]; int stok[10]; int spb[10]; };
union  SMU { SA a; SB b; SCD cd; SE e; SF_ f; SG g; SFN fin; };

// ---------------- the mega-kernel ----------------
__global__ __launch_bounds__(256) void mega_kernel(
    float* ws, const float* enc_key, const float* enc_values, const float* maskp,
    const float* embedding,
    const float* W_ih1, const float* W_hh1, const float* b_ih1, const float* b_hh1,
    const float* W_ih2, const float* W_hh2, const float* b_ih2, const float* b_hh2,
    const float* Wq, const float* bq, const float* Wc, const float* bc, float* out) {
  cg::grid_group grid = cg::this_grid();
  const int tid = threadIdx.x;
  const int B = blockIdx.x;
  __shared__ SMU sm;
  __shared__ int sctl[2];

  // ---- init ----
  if (B == 0) {
    double* stA = (double*)(ws + ST_A_F);
    for (int i = tid; i < 4480; i += 256) stA[i] = 0.0;
    float* mA = ws + META_A_F;
    if (tid < K_BEAM) {
      ((double*)(mA + M_SC))[tid] = 0.0;
      ((int*)(mA + M_FIN))[tid] = 0;
      ((int*)(mA + M_PREV))[tid] = SOS_TOK;
    }
    for (int i = tid; i < K_BEAM*SEQ_LEN; i += 256)
      ((int*)(mA + M_SEQ))[i] = SOS_TOK;
  }
  grid.sync();

  for (int step = 0; step < MAXLEN; ++step) {
    const int par = step & 1;
    const double* S = (const double*)(ws + (par==0 ? ST_A_F : ST_B_F));
    double*       D = (double*)(ws + (par==0 ? ST_B_F : ST_A_F));
    const float* msrc = ws + (par==0 ? META_A_F : META_B_F);
    float*       mdst = ws + (par==0 ? META_B_F : META_A_F);

    // ---- phase A: LSTM1 gates (blocks 0..39) ----
    if (B < 40) {
      const int bm = B >> 2, q4 = B & 3;
      if (tid == 0) {
        int pb, tok, fin; double sc;
        if (step == 0) {
          pb = bm; tok = ((const int*)(msrc+M_PREV))[bm];
          sc = ((const double*)(msrc+M_SC))[bm];
          fin = ((const int*)(msrc+M_FIN))[bm];
        } else {
          int f = ((const int*)(ws+PICKF_F))[bm];
          pb = f / V_SZ; tok = f - pb*V_SZ;
          pb = min(max(pb,0),K_BEAM-1); tok = min(max(tok,0),V_SZ-1);
          sc = ((const double*)(ws+PICKV_F))[bm];
          fin = ((const int*)(msrc+M_FIN))[pb] | (tok==EOS_TOK);
        }
        sctl[0] = pb; sctl[1] = tok;
        if (q4 == 0) {
          ((double*)(mdst+M_SC))[bm] = sc;
          ((int*)(mdst+M_FIN))[bm] = fin;
          ((int*)(mdst+M_PREV))[bm] = tok;
        }
      }
      __syncthreads();
      const int pb = sctl[0], tok = sctl[1];
      if (q4 == 0) {
        for (int p = tid; p < SEQ_LEN; p += 256) {
          int v = ((const int*)(msrc+M_SEQ))[pb*SEQ_LEN+p];
          if (step > 0 && p == step) v = tok;
          ((int*)(mdst+M_SEQ))[bm*SEQ_LEN+p] = v;
        }
      }
      if (tid < 128)      sm.a.xin[tid] = (double)embedding[(size_t)tok*E_SZ + tid];
      else if (tid < 192) sm.a.xin[tid] = S[SD_CTX + pb*Q_SZ + (tid-128)];
      if (tid < 128)      sm.a.h1p[tid] = S[SD_H1 + pb*H1_SZ + tid];
      __syncthreads();
      const int lr = tid & 127, half = tid >> 7;
      const int r = q4*128 + lr;
      if (half == 0) {
        double acc = (double)b_ih1[r] + (double)b_hh1[r];
        const float4* wi = (const float4*)(W_ih1 + (size_t)r*192);
        for (int j = 0; j < 40; ++j) {
          float4 w = wi[j];
          acc += (double)w.x * sm.a.xin[4*j];   acc += (double)w.y * sm.a.xin[4*j+1];
          acc += (double)w.z * sm.a.xin[4*j+2]; acc += (double)w.w * sm.a.xin[4*j+3];
        }
        sm.a.lo[lr] = acc;
      } else {
        double acc = 0.0;
        const float4* wi = (const float4*)(W_ih1 + (size_t)r*192);
        for (int j = 40; j < 48; ++j) {
          float4 w = wi[j];
          acc += (double)w.x * sm.a.xin[4*j];   acc += (double)w.y * sm.a.xin[4*j+1];
          acc += (double)w.z * sm.a.xin[4*j+2]; acc += (double)w.w * sm.a.xin[4*j+3];
        }
        const float4* wh = (const float4*)(W_hh1 + (size_t)r*128);
        for (int j = 0; j < 32; ++j) {
          float4 w = wh[j];
          acc += (double)w.x * sm.a.h1p[4*j];   acc += (double)w.y * sm.a.h1p[4*j+1];
          acc += (double)w.z * sm.a.h1p[4*j+2]; acc += (double)w.w * sm.a.h1p[4*j+3];
        }
        sm.a.hi[lr] = acc;
      }
      __syncthreads();
      if (tid < 128) ((double*)(ws+GT1_F))[bm*512 + r] = sm.a.lo[tid] + sm.a.hi[tid];
    }
    grid.sync();

    // ---- phase B: LSTM1 act + LSTM2 + q (blocks 0..9) ----
    if (B < 10) {
      const int b = B;
      if (tid == 0) {
        int pb;
        if (step == 0) pb = b;
        else {
          int f = ((const int*)(ws+PICKF_F))[b];
          pb = f / V_SZ; pb = min(max(pb,0),K_BEAM-1);
        }
        sctl[0] = pb;
      }
      __syncthreads();
      const int pb = sctl[0];
      const double* g1 = (const double*)(ws+GT1_F) + b*512;
      if (tid < 128) {
        double ig = 1.0/(1.0+exp(-g1[tid]));
        double fg = 1.0/(1.0+exp(-g1[128+tid]));
        double gg = tanh(g1[256+tid]);
        double og = 1.0/(1.0+exp(-g1[384+tid]));
        double c = fg * S[SD_C1 + pb*H1_SZ + tid] + ig*gg;
        double h = og * tanh(c);
        D[SD_C1 + b*H1_SZ + tid] = c; D[SD_H1 + b*H1_SZ + tid] = h;
        sm.b.h1n[tid] = h;
      }
      if (tid < 64) sm.b.h2p[tid] = S[SD_H2 + pb*H2_SZ + tid];
      __syncthreads();
      {
        int r = tid;
        double acc = (double)b_ih2[r] + (double)b_hh2[r];
        const float4* wi = (const float4*)(W_ih2 + (size_t)r*128);
        for (int j = 0; j < 32; ++j) {
          float4 w = wi[j];
          acc += (double)w.x * sm.b.h1n[4*j];   acc += (double)w.y * sm.b.h1n[4*j+1];
          acc += (double)w.z * sm.b.h1n[4*j+2]; acc += (double)w.w * sm.b.h1n[4*j+3];
        }
        const float4* wh = (const float4*)(W_hh2 + (size_t)r*64);
        for (int j = 0; j < 16; ++j) {
          float4 w = wh[j];
          acc += (double)w.x * sm.b.h2p[4*j];   acc += (double)w.y * sm.b.h2p[4*j+1];
          acc += (double)w.z * sm.b.h2p[4*j+2]; acc += (double)w.w * sm.b.h2p[4*j+3];
        }
        sm.b.gt2[r] = acc;
      }
      __syncthreads();
      if (tid < 64) {
        double ig = 1.0/(1.0+exp(-sm.b.gt2[tid]));
        double fg = 1.0/(1.0+exp(-sm.b.gt2[64+tid]));
        double gg = tanh(sm.b.gt2[128+tid]);
        double og = 1.0/(1.0+exp(-sm.b.gt2[192+tid]));
        double c = fg * S[SD_C2 + pb*H2_SZ + tid] + ig*gg;
        double h = og * tanh(c);
        D[SD_C2 + b*H2_SZ + tid] = c; D[SD_H2 + b*H2_SZ + tid] = h;
        sm.b.h2n[tid] = h;
        ((double*)(ws+H2V_F))[b*64+tid] = h;
      }
      __syncthreads();
      if (tid < 64) {
        double acc = (double)bq[tid];
        const float4* wr = (const float4*)(Wq + (size_t)tid*64);
        for (int j = 0; j < 16; ++j) {
          float4 w = wr[j];
          acc += (double)w.x * sm.b.h2n[4*j];   acc += (double)w.y * sm.b.h2n[4*j+1];
          acc += (double)w.z * sm.b.h2n[4*j+2]; acc += (double)w.w * sm.b.h2n[4*j+3];
        }
        ((double*)(ws+QD_F))[b*64+tid] = acc;
      }
    }
    grid.sync();

    // ---- phase C: energy chunks (blocks 0..79); energies stay in LDS ----
    if (B < 80) {
      const int bm = B >> 3, ch = B & 7;
      if (tid < 64) sm.cd.qs[tid] = ((const double*)(ws+QD_F))[bm*64+tid];
      __syncthreads();
      const int t = ch*256 + tid;
      const float4* kr = (const float4*)(enc_key + (size_t)t*64);
      double e = 0.0;
      for (int j = 0; j < 16; ++j) {
        float4 k = kr[j];
        e += (double)k.x * sm.cd.qs[4*j];   e += (double)k.y * sm.cd.qs[4*j+1];
        e += (double)k.z * sm.cd.qs[4*j+2]; e += (double)k.w * sm.cd.qs[4*j+3];
      }
      sm.cd.es[tid] = e;
      sm.cd.rm[tid] = e; sm.cd.rs[tid] = 1.0;
      __syncthreads();
      for (int s2 = 128; s2 > 0; s2 >>= 1) {
        if (tid < s2) {
          double m1 = sm.cd.rm[tid], m2 = sm.cd.rm[tid+s2];
          double nm = fmax(m1, m2);
          sm.cd.rs[tid] = sm.cd.rs[tid]*exp(m1-nm) + sm.cd.rs[tid+s2]*exp(m2-nm);
          sm.cd.rm[tid] = nm;
        }
        __syncthreads();
      }
      if (tid == 0) {
        ((double*)(ws+MC_F))[bm*8+ch]  = sm.cd.rm[0];
        ((double*)(ws+SCC_F))[bm*8+ch] = sm.cd.rs[0];
      }
    }
    grid.sync();

    // ---- phase D: matt + chunk msum/ctx partials (same blocks; es persists) --
    if (B < 80) {
      const int bm = B >> 3, ch = B & 7;
      if (tid == 0) {
        double m = -1e300, s = 0.0;
        for (int c = 0; c < 8; ++c) {
          double mc = ((const double*)(ws+MC_F))[bm*8+c];
          double sc = ((const double*)(ws+SCC_F))[bm*8+c];
          double nm = fmax(m, mc);
          s = s*exp(m-nm) + sc*exp(mc-nm);
          m = nm;
        }
        sm.cd.mx = m; sm.cd.Ss = s;
      }
      __syncthreads();
      const double mx = sm.cd.mx, Ss = sm.cd.Ss;
      const int t = ch*256 + tid;
      double matt = (double)maskp[t] * (exp(sm.cd.es[tid]-mx)/Ss);
      sm.cd.rm[tid] = matt; __syncthreads();
      for (int s2 = 128; s2 > 0; s2 >>= 1) {
        if (tid < s2) sm.cd.rm[tid] += sm.cd.rm[tid+s2];
        __syncthreads();
      }
      if (tid == 0) ((double*)(ws+MSC_F))[bm*8+ch] = sm.cd.rm[0];
      __syncthreads();
      const int v = tid & 63, g4 = tid >> 6;
      double acc = 0.0;
      for (int kk = 0; kk < 64; ++kk) {
        int tl = g4 + 4*kk;
        double mt = (double)maskp[ch*256+tl] * (exp(sm.cd.es[tl]-mx)/Ss);
        acc += mt * (double)enc_values[(size_t)(ch*256+tl)*64 + v];
      }
      sm.cd.rm[tid] = acc; __syncthreads();
      if (g4 == 0)
        ((double*)(ws+CTXC_F))[(bm*8+ch)*64 + v] =
          sm.cd.rm[v]+sm.cd.rm[64+v]+sm.cd.rm[128+v]+sm.cd.rm[192+v];
    }
    grid.sync();

    // ---- phase E: ctx fold + logits + lse partials + block top-10 (all) ----
    {
      const int bb = B;
      const int v0 = bb*VC, vn = min(VC, V_SZ - v0);
      for (int idx = tid; idx < 640; idx += 256) {
        int b = idx >> 6, v = idx & 63;
        sm.e.xs[b*128 + v] = ((const double*)(ws+H2V_F))[b*64+v];
        double ms = 0.0;
        for (int c = 0; c < 8; ++c) ms += ((const double*)(ws+MSC_F))[b*8+c];
        ms = fmax(ms, 2e-30);
        double cv = 0.0;
        for (int c = 0; c < 8; ++c) cv += ((const double*)(ws+CTXC_F))[(b*8+c)*64+v];
        cv /= ms;
        sm.e.xs[b*128 + 64 + v] = cv;
        if (bb == 0) D[SD_CTX + b*64 + v] = cv;
      }
      __syncthreads();
      for (int vl = tid; vl < vn; vl += 256) {
        const float4* wr = (const float4*)(Wc + (size_t)(v0+vl)*128);
        double acc[K_BEAM];
        #pragma unroll
        for (int b = 0; b < K_BEAM; ++b) acc[b] = 0.0;
        for (int j = 0; j < 32; ++j) {
          float4 w = wr[j];
          double w0 = (double)w.x, w1 = (double)w.y, w2 = (double)w.z, w3 = (double)w.w;
          #pragma unroll
          for (int b = 0; b < K_BEAM; ++b) acc[b] += w0 * sm.e.xs[b*128 + 4*j];
          #pragma unroll
          for (int b = 0; b < K_BEAM; ++b) acc[b] += w1 * sm.e.xs[b*128 + 4*j + 1];
          #pragma unroll
          for (int b = 0; b < K_BEAM; ++b) acc[b] += w2 * sm.e.xs[b*128 + 4*j + 2];
          #pragma unroll
          for (int b = 0; b < K_BEAM; ++b) acc[b] += w3 * sm.e.xs[b*128 + 4*j + 3];
        }
        double bcv = (double)bc[v0+vl];
        #pragma unroll
        for (int b = 0; b < K_BEAM; ++b) sm.e.lg[vl*K_BEAM + b] = (float)(acc[b] + bcv);
      }
      __syncthreads();
      const int lane = tid & 63, w = tid >> 6;
      for (int b = w; b < K_BEAM; b += 4) {
        double m = -1e300, s = 0.0;
        for (int vl = lane; vl < vn; vl += 64) {
          double val = (double)sm.e.lg[vl*K_BEAM + b];
          double nm = fmax(m, val);
          s = s * exp(m - nm) + exp(val - nm);
          m = nm;
        }
        #pragma unroll
        for (int off = 32; off > 0; off >>= 1) {
          double om = __shfl_down(m, off, 64);
          double os = __shfl_down(s, off, 64);
          double nm = fmax(m, om);
          s = s * exp(m - nm) + os * exp(om - nm);
          m = nm;
        }
        if (lane == 0) {
          ((double*)(ws+LSEM_F))[bb*K_BEAM + b] = m;
          ((double*)(ws+LSES_F))[bb*K_BEAM + b] = s;
        }
        int taken[10];
        for (int pick = 0; pick < 10; ++pick) {
          float bv = -3e38f; int bi = 0x7ffffff0;
          for (int vl = lane; vl < vn; vl += 64) {
            bool skip = false;
            for (int q = 0; q < pick; ++q) skip = skip || (taken[q] == vl);
            if (!skip) {
              float val = sm.e.lg[vl*K_BEAM + b];
              if (val > bv || (val == bv && vl < bi)) { bv = val; bi = vl; }
            }
          }
          float wv = bv; int wi = bi;
          wave_argmax_f(wv, wi);
          wv = __shfl(wv, 0, 64); wi = __shfl(wi, 0, 64);
          taken[pick] = wi;
          wi = min(max(wi, 0), vn - 1);
          if (lane == 0) {
            (ws+CANDV_F)[(bb*K_BEAM + b)*10 + pick] = wv;
            ((int*)(ws+CANDI_F))[(bb*K_BEAM + b)*10 + pick] = v0 + wi;
          }
        }
      }
    }
    grid.sync();

    // ---- phase F: per-(beam,slice) select 320 -> 10 + slice lse (blocks 0..79)
    if (B < 80) {
      const int b = B >> 3, sl = B & 7;
      if (tid < 32) {
        sm.f.lm[tid] = ((const double*)(ws+LSEM_F))[(sl*32+tid)*K_BEAM + b];
        sm.f.ls[tid] = ((const double*)(ws+LSES_F))[(sl*32+tid)*K_BEAM + b];
      }
      for (int c = tid; c < 320; c += 256) {
        int cb = sl*32 + c/10, j = c - (c/10)*10;
        sm.f.cv[c] = (ws+CANDV_F)[(cb*K_BEAM + b)*10 + j];
        sm.f.ci[c] = ((const int*)(ws+CANDI_F))[(cb*K_BEAM + b)*10 + j];
      }
      __syncthreads();
      for (int s2 = 16; s2 > 0; s2 >>= 1) {
        if (tid < s2) {
          double m1 = sm.f.lm[tid], m2 = sm.f.lm[tid+s2];
          double nm = fmax(m1, m2);
          sm.f.ls[tid] = sm.f.ls[tid]*exp(m1-nm) + sm.f.ls[tid+s2]*exp(m2-nm);
          sm.f.lm[tid] = nm;
        }
        __syncthreads();
      }
      if (tid == 0) {
        ((double*)(ws+SLM_F))[b*8+sl] = sm.f.lm[0];
        ((double*)(ws+SLS_F))[b*8+sl] = sm.f.ls[0];
      }
      for (int pick = 0; pick < 10; ++pick) {
        float bv = -3e38f; int bi = 0x7ffffff0;
        for (int c = tid; c < 320; c += 256) {
          bool ex = false;
          for (int q = 0; q < pick; ++q) ex = ex || (sm.f.pi[q] == sm.f.ci[c]);
          if (!ex) {
            float val = sm.f.cv[c]; int ii = sm.f.ci[c];
            if (val > bv || (val == bv && ii < bi)) { bv = val; bi = ii; }
          }
        }
        sm.f.rv[tid] = bv; sm.f.ri[tid] = bi;
        __syncthreads();
        for (int s2 = 128; s2 > 0; s2 >>= 1) {
          if (tid < s2) {
            if (sm.f.rv[tid+s2] > sm.f.rv[tid] ||
                (sm.f.rv[tid+s2] == sm.f.rv[tid] && sm.f.ri[tid+s2] < sm.f.ri[tid])) {
              sm.f.rv[tid] = sm.f.rv[tid+s2]; sm.f.ri[tid] = sm.f.ri[tid+s2];
            }
          }
          __syncthreads();
        }
        if (tid == 0) { sm.f.pv[pick] = sm.f.rv[0]; sm.f.pi[pick] = sm.f.ri[0]; }
        __syncthreads();
      }
      if (tid < 10) {
        (ws+SV_F)[(b*8+sl)*10 + tid] = sm.f.pv[tid];
        ((int*)(ws+SF_F))[(b*8+sl)*10 + tid] = sm.f.pi[tid];
      }
    }
    grid.sync();

    // ---- phase G: per-beam merge + global top-10 (block 0) ----
    if (B == 0) {
      const int lane = tid & 63, w = tid >> 6;
      for (int b = w; b < K_BEAM; b += 4) {
        double sc = ((const double*)(mdst+M_SC))[b];
        int fin = ((const int*)(mdst+M_FIN))[b];
        double lse = 0.0;
        if (lane == 0) {
          double m = -1e300, s = 0.0;
          for (int k = 0; k < 8; ++k) {
            double pm = ((const double*)(ws+SLM_F))[b*8+k];
            double ps = ((const double*)(ws+SLS_F))[b*8+k];
            double nm = fmax(m, pm);
            s = s*exp(m-nm) + ps*exp(pm-nm);
            m = nm;
          }
          lse = m + log(s);
        }
        lse = __shfl(lse, 0, 64);
        float rv[2]; int ri[2];
        #pragma unroll
        for (int r = 0; r < 2; ++r) {
          int c = lane + 64*r;
          if (c < 80) { rv[r] = (ws+SV_F)[b*80 + c]; ri[r] = ((const int*)(ws+SF_F))[b*80 + c]; }
          else        { rv[r] = -3e38f; ri[r] = 0x7ffffff0; }
        }
        for (int pick = 0; pick < 10; ++pick) {
          float bv = rv[0]; int bi = ri[0];
          if (rv[1] > bv || (rv[1] == bv && ri[1] < bi)) { bv = rv[1]; bi = ri[1]; }
          wave_argmax_f(bv, bi);
          bv = __shfl(bv, 0, 64); bi = __shfl(bi, 0, 64);
          if (lane == 0) {
            double val; int flat;
            if (fin) {
              val = (pick == 0) ? sc : -1e301;
              flat = (pick == 0) ? (b*V_SZ + EOS_TOK) : 0x7ffffff0;
            } else if (step == 0 && b > 0) {
              val = -1e301; flat = 0x7ffffff0;
            } else {
              val = sc - lse + (double)bv; flat = b*V_SZ + bi;
            }
            sm.g.gv[b*10+pick] = val; sm.g.gf[b*10+pick] = flat;
          }
          #pragma unroll
          for (int r = 0; r < 2; ++r)
            if (ri[r] == bi) { rv[r] = -3e38f; ri[r] = 0x7ffffff0; }
        }
      }
      __syncthreads();
      if (w == 0) {
        double av[2]; int af[2];
        #pragma unroll
        for (int r = 0; r < 2; ++r) {
          int c = lane + 64*r;
          if (c < 100) { av[r] = sm.g.gv[c]; af[r] = sm.g.gf[c]; }
          else         { av[r] = -1e302; af[r] = 0x7fffffff; }
        }
        for (int pick = 0; pick < 10; ++pick) {
          double bv = av[0]; int bf = af[0];
          if (av[1] > bv || (av[1] == bv && af[1] < bf)) { bv = av[1]; bf = af[1]; }
          wave_argmax_d(bv, bf);
          bv = __shfl(bv, 0, 64); bf = __shfl(bf, 0, 64);
          if (lane == 0) {
            ((double*)(ws+PICKV_F))[pick] = bv;
            ((int*)(ws+PICKF_F))[pick] = bf;
          }
          #pragma unroll
          for (int r = 0; r < 2; ++r)
            if (af[r] == bf) { av[r] = -1e302; af[r] = 0x7fffffff; }
        }
      }
    }
    grid.sync();
  }

  // ---- final: gather + lengths + output (block 0) ----
  if (B == 0) {
    const float* mA = ws + META_A_F;     // dst of step 29 (odd -> A)
    const int* seqA = (const int*)(mA + M_SEQ);
    const double* pvv = (const double*)(ws + PICKV_F);
    const int* pfv = (const int*)(ws + PICKF_F);
    if (tid < K_BEAM) {
      int f = pfv[tid];
      int pb = f / V_SZ, tk = f - pb*V_SZ;
      sm.fin.spb[tid] = min(max(pb, 0), K_BEAM - 1);
      sm.fin.stok[tid] = min(max(tk, 0), V_SZ - 1);
    }
    __syncthreads();
    for (int t = tid; t < K_BEAM*SEQ_LEN; t += 256) {
      int j = t / SEQ_LEN, p = t - j*SEQ_LEN;
      sm.fin.seqF[t] = (p == MAXLEN) ? sm.fin.stok[j] : seqA[sm.fin.spb[j]*SEQ_LEN + p];
    }
    __syncthreads();
    if (tid < K_BEAM) {
      int first = -1;
      for (int p = 1; p <= MAXLEN; ++p)
        if (sm.fin.seqF[tid*SEQ_LEN + p] == EOS_TOK) { first = p - 1; break; }
      double len = (first >= 0) ? (double)(first + 2) : (double)(MAXLEN + 2);
      double scv = pvv[tid];
      out[K_BEAM*SEQ_LEN + tid] = (float)scv;
      out[K_BEAM*SEQ_LEN + K_BEAM + tid] = (float)(scv / pow(len, 1.2));
    }
    for (int t = tid; t < K_BEAM*SEQ_LEN; t += 256) out[t] = (float)sm.fin.seqF[t];
  }
}

// ---------------- host ----------------
extern "C" void kernel_launch(void* const* d_in, const int* in_sizes, int n_in,
                              void* d_out, int out_size, void* d_ws, size_t ws_size,
                              hipStream_t stream) {
  float* ws  = (float*)d_ws;
  float* out = (float*)d_out;
  const float* enc_key    = (const float*)d_in[0];
  const float* enc_values = (const float*)d_in[1];
  const float* maskp      = (const float*)d_in[2];
  const float* embedding  = (const float*)d_in[3];
  const float* W_ih1      = (const float*)d_in[4];
  const float* W_hh1      = (const float*)d_in[5];
  const float* b_ih1      = (const float*)d_in[6];
  const float* b_hh1      = (const float*)d_in[7];
  const float* W_ih2      = (const float*)d_in[8];
  const float* W_hh2      = (const float*)d_in[9];
  const float* b_ih2      = (const float*)d_in[10];
  const float* b_hh2      = (const float*)d_in[11];
  const float* Wq         = (const float*)d_in[12];
  const float* bq         = (const float*)d_in[13];
  const float* Wc         = (const float*)d_in[14];
  const float* bc         = (const float*)d_in[15];

  void* args[] = {
    (void*)&ws, (void*)&enc_key, (void*)&enc_values, (void*)&maskp,
    (void*)&embedding, (void*)&W_ih1, (void*)&W_hh1, (void*)&b_ih1, (void*)&b_hh1,
    (void*)&W_ih2, (void*)&W_hh2, (void*)&b_ih2, (void*)&b_hh2,
    (void*)&Wq, (void*)&bq, (void*)&Wc, (void*)&bc, (void*)&out
  };
  hipLaunchCooperativeKernel((void*)mega_kernel, dim3(NBLK), dim3(256), args, 0, stream);
}